// Round 2
// baseline (107.169 us; speedup 1.0000x reference)
//
#include <hip/hip_runtime.h>
#include <hip/hip_bf16.h>

#define D_ 256
#define HW_ 1024
#define K_ 1024

typedef short short8 __attribute__((ext_vector_type(8)));
typedef float float4v __attribute__((ext_vector_type(4)));

__device__ __forceinline__ unsigned short f2bf(float f) {
  unsigned u = __builtin_bit_cast(unsigned, f);
  return (unsigned short)((u + 0x7fffu + ((u >> 16) & 1u)) >> 16);
}

__device__ __forceinline__ void async16(void* lds, const void* g) {
  __builtin_amdgcn_global_load_lds(
      (__attribute__((address_space(1))) const unsigned int*)g,
      (__attribute__((address_space(3))) unsigned int*)lds, 16, 0, 0);
}

// ---------------- prep: cnorm + bf16(-2c) swizzled image, 64-code chunks -------
// chunk ch (64 codes): row=k&63 of 512B; byte for feature d at (2d)^((row&15)<<5)
__global__ __launch_bounds__(256) void vq_prep(const float* __restrict__ cb,
                                               unsigned short* __restrict__ cbimg,
                                               float* __restrict__ cnorm) {
  int k = blockIdx.x;   // 0..1023
  int t = threadIdx.x;  // 0..255
  float c = cb[k * D_ + t];
  float s = c * c;
#pragma unroll
  for (int off = 1; off < 64; off <<= 1) s += __shfl_xor(s, off, 64);
  __shared__ float wsum[4];
  if ((t & 63) == 0) wsum[t >> 6] = s;
  __syncthreads();
  if (t == 0) cnorm[k] = wsum[0] + wsum[1] + wsum[2] + wsum[3];
  int row = k & 63, chunk = k >> 6;
  int byteoff = (2 * t) ^ ((row & 15) << 5);
  *(unsigned short*)((char*)cbimg + chunk * 32768 + row * 512 + byteoff) = f2bf(-2.0f * c);
}

// ---------------- xpose: latents [B,D,HW] fp32 -> bf16 B-fragment image --------
// limg layout: 16-pt group g, k-chunk kk(32 feats): 1KB block of 64 lanes x 16B;
// lane = q*16 + c holds point (g*16+c) features kk*32+q*8 .. +7.
__global__ __launch_bounds__(256) void vq_xpose(const float* __restrict__ lat,
                                                short8* __restrict__ limg) {
  __shared__ unsigned short tile[16384];  // 64 hw x 256 d bf16, swizzled, 32KB
  int t = threadIdx.x;
  int bb = blockIdx.x >> 4;
  int hw0 = (blockIdx.x & 15) * 64;
  const int dsub = t >> 4;
  const int hwb = (t & 15) * 4;
#pragma unroll
  for (int it = 0; it < 16; ++it) {
    int d = it * 16 + dsub;
    float4v v = *(const float4v*)&lat[((size_t)(bb * D_ + d)) * HW_ + hw0 + hwb];
#pragma unroll
    for (int i = 0; i < 4; ++i) {
      int hw = hwb + i;
      int slot = (d >> 3) ^ ((hw & 15) << 1);  // same swizzle family as cbimg
      tile[hw * 256 + (slot << 3) + (d & 7)] = f2bf(v[i]);
    }
  }
  __syncthreads();
  int q = t >> 6, hw = t & 63;
  int grp = blockIdx.x * 4 + (hw >> 4);
  int c = hw & 15;
#pragma unroll
  for (int kk = 0; kk < 8; ++kk) {
    int slot = ((kk << 2) | q) ^ ((hw & 15) << 1);
    short8 v = *(const short8*)&tile[hw * 256 + (slot << 3)];
    limg[((size_t)grp * 8 + kk) * 64 + q * 16 + c] = v;
  }
}

// ---------------- main: distances + argmin + loss partials ---------------------
// 256 blocks x 256 thr (4 waves). Wave pg owns 64 pts (pf=4 groups of 16).
// Each wave covers all 64 codes of a chunk (af=4): no cross-wave merge needed.
__global__ __launch_bounds__(256, 2) void vq_main(const short8* __restrict__ limg,
                                                  const short8* __restrict__ cbimg,
                                                  const float* __restrict__ cnorm,
                                                  int* __restrict__ idx_out,
                                                  float* __restrict__ part) {
  __shared__ short8 cbA[2][2048];   // 2 x 32KB
  __shared__ float cnorm_s[1024];

  const int tid = threadIdx.x;
  const int pg = tid >> 6, lane = tid & 63;
  const int q = lane >> 4, c = lane & 15;
  const int pt0 = blockIdx.x * 256;

  cnorm_s[tid] = cnorm[tid];
  cnorm_s[tid + 256] = cnorm[tid + 256];
  cnorm_s[tid + 512] = cnorm[tid + 512];
  cnorm_s[tid + 768] = cnorm[tid + 768];

  // stage chunk 0
#pragma unroll
  for (int r = 0; r < 8; ++r)
    async16(&cbA[0][r * 256 + tid], cbimg + (r * 256 + tid));

  // B-frags: fully coalesced 1KB wave loads from the fragment image
  short8 bfrag[4][8];
  const int grpbase = blockIdx.x * 16 + pg * 4;
#pragma unroll
  for (int pf = 0; pf < 4; ++pf)
#pragma unroll
    for (int kk = 0; kk < 8; ++kk)
      bfrag[pf][kk] = limg[(size_t)((grpbase + pf) * 8 + kk) * 64 + lane];

  // |f|^2 from bf16 values (loss tolerance >> bf16 rounding)
  float fn[4];
#pragma unroll
  for (int pf = 0; pf < 4; ++pf) {
    float a = 0.f;
#pragma unroll
    for (int kk = 0; kk < 8; ++kk)
#pragma unroll
      for (int j = 0; j < 8; ++j) {
        unsigned u = ((unsigned)(unsigned short)bfrag[pf][kk][j]) << 16;
        float f = __builtin_bit_cast(float, u);
        a += f * f;
      }
    fn[pf] = a;
  }
#pragma unroll
  for (int pf = 0; pf < 4; ++pf) {
    fn[pf] += __shfl_xor(fn[pf], 16, 64);
    fn[pf] += __shfl_xor(fn[pf], 32, 64);
  }

  float runD[4];
  int runI[4];
#pragma unroll
  for (int pf = 0; pf < 4; ++pf) { runD[pf] = 3.0e38f; runI[pf] = 0x7fffffff; }

  __syncthreads();  // chunk0 + cnorm_s ready

  int buf = 0;
  for (int chunk = 0; chunk < 16; ++chunk) {
    if (chunk < 15) {
#pragma unroll
      for (int r = 0; r < 8; ++r)
        async16(&cbA[buf ^ 1][r * 256 + tid],
                cbimg + ((chunk + 1) * 2048 + r * 256 + tid));
    }
    float4v acc[4][4];
#pragma unroll
    for (int af = 0; af < 4; ++af) {
      float4v cn = *(const float4v*)&cnorm_s[chunk * 64 + af * 16 + q * 4];
#pragma unroll
      for (int pf = 0; pf < 4; ++pf) acc[af][pf] = cn;
    }
#pragma unroll
    for (int kk = 0; kk < 8; ++kk) {
      short8 a[4];
#pragma unroll
      for (int af = 0; af < 4; ++af)
        a[af] = cbA[buf][(af * 16 + c) * 32 + (((kk << 2) | q) ^ (c << 1))];
#pragma unroll
      for (int af = 0; af < 4; ++af)
#pragma unroll
        for (int pf = 0; pf < 4; ++pf)
          acc[af][pf] = __builtin_amdgcn_mfma_f32_16x16x32_bf16(
              a[af], bfrag[pf][kk], acc[af][pf], 0, 0, 0);
    }
    // argmin epilogue (first-occurrence tie-break)
#pragma unroll
    for (int pf = 0; pf < 4; ++pf) {
      float md = 3.0e38f;
      int mi = 0x7fffffff;
#pragma unroll
      for (int af = 0; af < 4; ++af) {
        int cb0 = chunk * 64 + af * 16 + q * 4;
#pragma unroll
        for (int r = 0; r < 4; ++r) {
          float dv = acc[af][pf][r];
          if (dv < md) { md = dv; mi = cb0 + r; }
        }
      }
#pragma unroll
      for (int di = 16; di < 64; di <<= 1) {
        float od = __shfl_xor(md, di, 64);
        int oi = __shfl_xor(mi, di, 64);
        if (od < md || (od == md && oi < mi)) { md = od; mi = oi; }
      }
      if (md < runD[pf] || (md == runD[pf] && mi < runI[pf])) {
        runD[pf] = md; runI[pf] = mi;
      }
    }
    __syncthreads();
    buf ^= 1;
  }

  // lane writes point (pg, pf=q, c); q-lanes hold identical merged results
  float selD = q == 0 ? runD[0] : q == 1 ? runD[1] : q == 2 ? runD[2] : runD[3];
  int selI = q == 0 ? runI[0] : q == 1 ? runI[1] : q == 2 ? runI[2] : runI[3];
  float selF = q == 0 ? fn[0] : q == 1 ? fn[1] : q == 2 ? fn[2] : fn[3];
  idx_out[pt0 + pg * 64 + q * 16 + c] = selI;
  float lv = selD + selF;  // ||f - c_best||^2
#pragma unroll
  for (int off = 1; off < 64; off <<= 1) lv += __shfl_xor(lv, off, 64);
  if (lane == 0) part[blockIdx.x * 4 + pg] = lv;
}

// ---------------- gather: out[b,d,h,w] = codebook[idx[n]][d], float4 stores ----
__global__ __launch_bounds__(256) void vq_gather(const float* __restrict__ cb,
                                                 const int* __restrict__ idx,
                                                 float* __restrict__ out) {
  __shared__ float qv[64][257];
  __shared__ int sidx[64];
  int t = threadIdx.x;
  int pt0 = blockIdx.x * 64;
  int b = pt0 >> 10, hw0 = pt0 & 1023;
  if (t < 64) sidx[t] = idx[pt0 + t];
  __syncthreads();
  for (int p = 0; p < 64; ++p) qv[p][t] = cb[(size_t)sidx[p] * D_ + t];
  __syncthreads();
  int hw4 = (t & 15) * 4, dsub = t >> 4;
#pragma unroll
  for (int it = 0; it < 16; ++it) {
    int d = it * 16 + dsub;
    float4v v;
    v[0] = qv[hw4][d]; v[1] = qv[hw4 + 1][d];
    v[2] = qv[hw4 + 2][d]; v[3] = qv[hw4 + 3][d];
    *(float4v*)&out[(size_t)(b * D_ + d) * HW_ + hw0 + hw4] = v;
  }
}

// ---------------- finalize: loss = 1.25 * mean ----------------
__global__ __launch_bounds__(256) void vq_fin(const float* __restrict__ part,
                                              float* __restrict__ outs) {
  int t = threadIdx.x;
  float s = part[t] + part[t + 256] + part[t + 512] + part[t + 768];
#pragma unroll
  for (int off = 1; off < 64; off <<= 1) s += __shfl_xor(s, off, 64);
  __shared__ float w4[4];
  if ((t & 63) == 0) w4[t >> 6] = s;
  __syncthreads();
  if (t == 0) *outs = (w4[0] + w4[1] + w4[2] + w4[3]) * (1.25f / 16777216.0f);
}

extern "C" void kernel_launch(void* const* d_in, const int* in_sizes, int n_in,
                              void* d_out, int out_size, void* d_ws, size_t ws_size,
                              hipStream_t stream) {
  const float* lat = (const float*)d_in[0];
  const float* cb = (const float*)d_in[1];
  float* out = (float*)d_out;
  char* ws = (char*)d_ws;
  unsigned short* cbimg = (unsigned short*)ws;     // 512 KB (bf16 -2c image)
  float* cnorm = (float*)(ws + 524288);            // 4 KB
  int* idxbuf = (int*)(ws + 528384);               // 256 KB
  float* partial = (float*)(ws + 790528);          // 4 KB

  // latent fragment image (32 MB) lives in the front of d_out; it is fully
  // consumed by vq_main before vq_gather overwrites d_out (same stream).
  short8* limg = (short8*)d_out;

  vq_prep<<<1024, 256, 0, stream>>>(cb, cbimg, cnorm);
  vq_xpose<<<1024, 256, 0, stream>>>(lat, limg);
  vq_main<<<256, 256, 0, stream>>>(limg, (const short8*)cbimg, cnorm, idxbuf, partial);
  vq_gather<<<1024, 256, 0, stream>>>(cb, idxbuf, out);
  vq_fin<<<1, 256, 0, stream>>>(partial, out + 16777216);
}

// Round 3
// 71.721 us; speedup vs baseline: 1.4942x; 1.4942x over previous
//
#include <hip/hip_runtime.h>
#include <hip/hip_bf16.h>

#define D_ 256
#define HW_ 1024
#define K_ 1024

typedef short short8 __attribute__((ext_vector_type(8)));
typedef float float4v __attribute__((ext_vector_type(4)));

__device__ __forceinline__ unsigned short f2bf(float f) {
  unsigned u = __builtin_bit_cast(unsigned, f);
  return (unsigned short)((u + 0x7fffu + ((u >> 16) & 1u)) >> 16);
}

__device__ __forceinline__ void async16(void* lds, const void* g) {
  __builtin_amdgcn_global_load_lds(
      (__attribute__((address_space(1))) const unsigned int*)g,
      (__attribute__((address_space(3))) unsigned int*)lds, 16, 0, 0);
}

// ---------------- prep: cnorm + bf16(-2c) swizzled image, 64-code chunks -------
// chunk ch (64 codes): row=k&63, 512B/row; byte for feature d at (2d)^((row&15)<<5)
__global__ __launch_bounds__(256) void vq_prep(const float* __restrict__ cb,
                                               unsigned short* __restrict__ cbimg,
                                               float* __restrict__ cnorm) {
  int k = blockIdx.x;   // 0..1023
  int t = threadIdx.x;  // 0..255
  float c = cb[k * D_ + t];
  float s = c * c;
#pragma unroll
  for (int off = 1; off < 64; off <<= 1) s += __shfl_xor(s, off, 64);
  __shared__ float wsum[4];
  if ((t & 63) == 0) wsum[t >> 6] = s;
  __syncthreads();
  if (t == 0) cnorm[k] = wsum[0] + wsum[1] + wsum[2] + wsum[3];
  int row = k & 63, chunk = k >> 6;
  int byteoff = (2 * t) ^ ((row & 15) << 5);
  *(unsigned short*)((char*)cbimg + chunk * 32768 + row * 512 + byteoff) = f2bf(-2.0f * c);
}

// ---------------- main: transpose-stage + distances + argmin + loss ------------
// grid 512, 256 thr (4 waves), 128 pts/block, 2 blocks/CU.
// wave w: pg=w>>1 (64 pts), ch=w&1 (32 of 64 codes per chunk).
__global__ __launch_bounds__(256, 2) void vq_main(const float* __restrict__ lat,
                                                  const short8* __restrict__ cbimg,
                                                  const float* __restrict__ cnorm,
                                                  int* __restrict__ idx_out,
                                                  float* __restrict__ part) {
  __shared__ short8 bufs[2][2048];   // 2 x 32KB: point tiles, then cb dbuf
  __shared__ float mergeD[128];
  __shared__ int mergeI[128];

  const int tid = threadIdx.x;
  const int w = tid >> 6, lane = tid & 63;
  const int pg = w >> 1, ch = w & 1;
  const int q = lane >> 4, c = lane & 15;
  const int pt0 = blockIdx.x * 128;
  const int b = pt0 >> 10, hw0 = pt0 & 1023;

  // ---- phase 1: stage 128 points (2 tiles of 64) fp32 -> bf16 swizzled LDS ----
  {
    const int dsub = tid >> 4;         // 0..15
    const int hwb = (tid & 15) * 4;
#pragma unroll
    for (int tile = 0; tile < 2; ++tile) {
#pragma unroll
      for (int it = 0; it < 16; ++it) {
        int d = it * 16 + dsub;
        float4v v = *(const float4v*)
            &lat[((size_t)(b * D_ + d)) * HW_ + hw0 + tile * 64 + hwb];
#pragma unroll
        for (int i = 0; i < 4; ++i) {
          int hw = hwb + i;
          int slot = (d >> 3) ^ ((hw & 15) << 1);
          ((unsigned short*)&bufs[tile][0])[hw * 256 + slot * 8 + (d & 7)] = f2bf(v[i]);
        }
      }
    }
  }
  __syncthreads();

  // ---- phase 2: read B-frags into registers (verified swizzle pattern) ----
  short8 bfrag[4][8];
#pragma unroll
  for (int pf = 0; pf < 4; ++pf)
#pragma unroll
    for (int kk = 0; kk < 8; ++kk) {
      int hw = pf * 16 + c;
      int slot = ((kk << 2) | q) ^ (c << 1);
      bfrag[pf][kk] = *(const short8*)((unsigned short*)&bufs[pg][0] + hw * 256 + slot * 8);
    }

  // |f|^2 from bf16 values (tolerance >> bf16 rounding; matches R2 numerics)
  float fn[4];
#pragma unroll
  for (int pf = 0; pf < 4; ++pf) {
    float a = 0.f;
#pragma unroll
    for (int kk = 0; kk < 8; ++kk)
#pragma unroll
      for (int j = 0; j < 8; ++j) {
        unsigned u = ((unsigned)(unsigned short)bfrag[pf][kk][j]) << 16;
        float f = __builtin_bit_cast(float, u);
        a += f * f;
      }
    fn[pf] = a;
  }
#pragma unroll
  for (int pf = 0; pf < 4; ++pf) {
    fn[pf] += __shfl_xor(fn[pf], 16, 64);
    fn[pf] += __shfl_xor(fn[pf], 32, 64);
  }
  __syncthreads();  // point tiles consumed; bufs now free for codebook stream

  // ---- phase 3: stream codebook chunks, accumulate lane-local argmin ----
  float runD[4];
  int runI[4];
#pragma unroll
  for (int pf = 0; pf < 4; ++pf) { runD[pf] = 3.0e38f; runI[pf] = 0x7fffffff; }

#pragma unroll
  for (int r = 0; r < 8; ++r)                       // prologue: chunk 0 -> buf 0
    async16(&bufs[0][r * 256 + tid], cbimg + (r * 256 + tid));
  __syncthreads();                                   // implies vmcnt(0)

  int buf = 0;
#pragma unroll 1
  for (int chunk = 0; chunk < 16; ++chunk) {
    if (chunk < 15) {
#pragma unroll
      for (int r = 0; r < 8; ++r)
        async16(&bufs[buf ^ 1][r * 256 + tid],
                cbimg + ((chunk + 1) * 2048 + r * 256 + tid));
    }
    float4v acc[2][4];
#pragma unroll
    for (int af = 0; af < 2; ++af) {
      float4v cn = *(const float4v*)&cnorm[chunk * 64 + ch * 32 + af * 16 + q * 4];
#pragma unroll
      for (int pf = 0; pf < 4; ++pf) acc[af][pf] = cn;
    }
#pragma unroll
    for (int kk = 0; kk < 8; ++kk) {
      short8 a[2];
#pragma unroll
      for (int af = 0; af < 2; ++af) {
        int row = ch * 32 + af * 16 + c;
        a[af] = bufs[buf][row * 32 + (((kk << 2) | q) ^ (c << 1))];
      }
#pragma unroll
      for (int af = 0; af < 2; ++af)
#pragma unroll
        for (int pf = 0; pf < 4; ++pf)
          acc[af][pf] = __builtin_amdgcn_mfma_f32_16x16x32_bf16(
              a[af], bfrag[pf][kk], acc[af][pf], 0, 0, 0);
    }
    // lane-local scan only (ascending code index => strict < keeps first occurrence)
#pragma unroll
    for (int pf = 0; pf < 4; ++pf)
#pragma unroll
      for (int af = 0; af < 2; ++af) {
        int cb0 = chunk * 64 + ch * 32 + af * 16 + q * 4;
#pragma unroll
        for (int r = 0; r < 4; ++r) {
          float dv = acc[af][pf][r];
          if (dv < runD[pf]) { runD[pf] = dv; runI[pf] = cb0 + r; }
        }
      }
    __syncthreads();
    buf ^= 1;
  }

  // ---- phase 4: one deferred butterfly + cross-wave merge ----
#pragma unroll
  for (int pf = 0; pf < 4; ++pf) {
#pragma unroll
    for (int di = 16; di < 64; di <<= 1) {
      float od = __shfl_xor(runD[pf], di, 64);
      int oi = __shfl_xor(runI[pf], di, 64);
      if (od < runD[pf] || (od == runD[pf] && oi < runI[pf])) {
        runD[pf] = od; runI[pf] = oi;
      }
    }
  }
  float selD = q == 0 ? runD[0] : q == 1 ? runD[1] : q == 2 ? runD[2] : runD[3];
  int selI = q == 0 ? runI[0] : q == 1 ? runI[1] : q == 2 ? runI[2] : runI[3];
  float selF = q == 0 ? fn[0] : q == 1 ? fn[1] : q == 2 ? fn[2] : fn[3];
  int p = pg * 64 + q * 16 + c;
  if (ch == 1) { mergeD[p] = selD; mergeI[p] = selI; }
  __syncthreads();
  if (ch == 0) {
    float od = mergeD[p];
    int oi = mergeI[p];
    if (od < selD || (od == selD && oi < selI)) { selD = od; selI = oi; }
    idx_out[pt0 + p] = selI;
    float lv = selD + selF;  // ||f - c_best||^2
#pragma unroll
    for (int off = 1; off < 64; off <<= 1) lv += __shfl_xor(lv, off, 64);
    if (lane == 0) part[blockIdx.x * 2 + pg] = lv;
  }
}

// ---------------- gather: out[b,d,h,w] = codebook[idx[n]][d], float4 stores ----
__global__ __launch_bounds__(256) void vq_gather(const float* __restrict__ cb,
                                                 const int* __restrict__ idx,
                                                 float* __restrict__ out) {
  __shared__ float qv[64][257];
  __shared__ int sidx[64];
  int t = threadIdx.x;
  int pt0 = blockIdx.x * 64;
  int b = pt0 >> 10, hw0 = pt0 & 1023;
  if (t < 64) sidx[t] = idx[pt0 + t];
  __syncthreads();
  for (int p = 0; p < 64; ++p) qv[p][t] = cb[(size_t)sidx[p] * D_ + t];
  __syncthreads();
  int hw4 = (t & 15) * 4, dsub = t >> 4;
#pragma unroll
  for (int it = 0; it < 16; ++it) {
    int d = it * 16 + dsub;
    float4v v;
    v[0] = qv[hw4][d]; v[1] = qv[hw4 + 1][d];
    v[2] = qv[hw4 + 2][d]; v[3] = qv[hw4 + 3][d];
    *(float4v*)&out[(size_t)(b * D_ + d) * HW_ + hw0 + hw4] = v;
  }
}

// ---------------- finalize: loss = 1.25 * mean ----------------
__global__ __launch_bounds__(256) void vq_fin(const float* __restrict__ part,
                                              float* __restrict__ outs) {
  int t = threadIdx.x;
  float s = part[t] + part[t + 256] + part[t + 512] + part[t + 768];
#pragma unroll
  for (int off = 1; off < 64; off <<= 1) s += __shfl_xor(s, off, 64);
  __shared__ float w4[4];
  if ((t & 63) == 0) w4[t >> 6] = s;
  __syncthreads();
  if (t == 0) *outs = (w4[0] + w4[1] + w4[2] + w4[3]) * (1.25f / 16777216.0f);
}

extern "C" void kernel_launch(void* const* d_in, const int* in_sizes, int n_in,
                              void* d_out, int out_size, void* d_ws, size_t ws_size,
                              hipStream_t stream) {
  const float* lat = (const float*)d_in[0];
  const float* cb = (const float*)d_in[1];
  float* out = (float*)d_out;
  char* ws = (char*)d_ws;
  unsigned short* cbimg = (unsigned short*)ws;     // 512 KB (bf16 -2c image)
  float* cnorm = (float*)(ws + 524288);            // 4 KB
  int* idxbuf = (int*)(ws + 528384);               // 256 KB
  float* partial = (float*)(ws + 790528);          // 4 KB (1024 floats)

  vq_prep<<<1024, 256, 0, stream>>>(cb, cbimg, cnorm);
  vq_main<<<512, 256, 0, stream>>>(lat, (const short8*)cbimg, cnorm, idxbuf, partial);
  vq_gather<<<1024, 256, 0, stream>>>(cb, idxbuf, out);
  vq_fin<<<1, 256, 0, stream>>>(partial, out + 16777216);
}